// Round 11
// baseline (1135.618 us; speedup 1.0000x reference)
//
#include <hip/hip_runtime.h>
#include <math.h>

// CurvatureLoss via 2D-cell-pruned exact KNN. B=2, N=8192, [B,N,3] fp32.
// sort: each set {tgt, src, warped=src+flow} into 64x64 (x,y) cells, cell-major.
// knn per query q = 8 lanes of ONE wave (wave-local sync only; LDS ops from a
// wave are pipeline-ordered, wave_barrier pins compiler order; NO block sync ->
// no straggler coupling across the block's 32 queries):
//   phase A: 128 cell-contiguous points centered on q's OWN slot/cell; per-lane
//     float top-4; leader merges pooled 32 -> T = K-th smallest (>= true K-th
//     distance: K-th order statistic of a >=K-subset of real candidates).
//   phase B: scan cells covering ball(q, sqrt(T)) with per-column circular
//     y-trim ry = sqrt(T - dx^2); buffer ALL d<=T points exactly once.
//   overflow fallback: if hits > CAP (rare), exact per-lane insert-rescan of
//     the same region -> correctness NEVER depends on CAP (r7/r9 bug fixed).
//   final: exact lex (d, orig_idx) top-K == jax.lax.top_k (unique keys =>
//     deterministic despite atomic scatter order).

constexpr int BLOCK = 256;
constexpr int NBX = 64, NBY = 64, NCELL = NBX * NBY;
constexpr float XLO = -6.0f, XHI = 6.0f;
constexpr float BKW = (XHI - XLO) / NBX;
constexpr float BKS = NBX / (XHI - XLO);
constexpr int AWIN = 128;          // per-query T-sample window
constexpr float RADIUS2 = 2.5f;

__device__ __forceinline__ float sq3(float x, float y, float z) {
    return fmaf(x, x, fmaf(y, y, z * z));
}
// stable ordering (matches jax.lax.top_k tie-break)
__device__ __forceinline__ bool lex_less(float d1, int i1, float d2, int i2) {
    return (d1 < d2) || (d1 == d2 && i1 < i2);
}
// monotone non-decreasing with clamp -> coverage stays exact
__device__ __forceinline__ int bkt_of(float v) {
    int k = (int)((v - XLO) * BKS);
    return k < 0 ? 0 : (k > NBX - 1 ? NBX - 1 : k);
}

// Cell-sort one (set,b): set 0=tgt, 1=src, 2=warped(src+flow). grid = 6 blocks.
__global__ __launch_bounds__(BLOCK)
void sort_kernel(const float* __restrict__ src, const float* __restrict__ tgt,
                 const float* __restrict__ flow,
                 float4* __restrict__ xyzw, int* __restrict__ sidx,
                 int* __restrict__ bstart, int N)
{
    const int set = blockIdx.x >> 1;
    const int b   = blockIdx.x & 1;
    const size_t pbase = (size_t)b * N * 3;
    const float* P = (set == 0) ? tgt : src;
    const bool addF = (set == 2);
    float4* oxy = xyzw + (size_t)blockIdx.x * N;
    int*    osx = sidx + (size_t)blockIdx.x * N;
    int*    obs = bstart + (size_t)blockIdx.x * (NCELL + 1);

    __shared__ int hist[NCELL];
    __shared__ int tsum[BLOCK];
    const int t = threadIdx.x;
    constexpr int CPT = NCELL / BLOCK;   // 16 cells per thread

    for (int k = t; k < NCELL; k += BLOCK) hist[k] = 0;
    __syncthreads();
    for (int i = t; i < N; i += BLOCK) {
        size_t o = pbase + (size_t)i * 3;
        float x = P[o], y = P[o + 1];
        if (addF) { x += flow[o]; y += flow[o + 1]; }
        atomicAdd(&hist[bkt_of(x) * NBY + bkt_of(y)], 1);
    }
    __syncthreads();
    {   // two-level exclusive scan
        int base = t * CPT, s = 0;
        for (int m = 0; m < CPT; ++m) s += hist[base + m];
        tsum[t] = s;
    }
    __syncthreads();
    if (t == 0) {
        int run = 0;
        for (int u = 0; u < BLOCK; ++u) { int v = tsum[u]; tsum[u] = run; run += v; }
    }
    __syncthreads();
    {
        int base = t * CPT, run = tsum[t];
        for (int m = 0; m < CPT; ++m) {
            int h = hist[base + m];
            hist[base + m] = run;          // scatter cursor
            obs[base + m] = run;           // cell start
            run += h;
        }
    }
    if (t == 0) obs[NCELL] = N;
    __syncthreads();
    for (int i = t; i < N; i += BLOCK) {
        size_t o = pbase + (size_t)i * 3;
        float x = P[o], y = P[o + 1], z = P[o + 2];
        if (addF) { x += flow[o]; y += flow[o + 1]; z += flow[o + 2]; }
        int pos = atomicAdd(&hist[bkt_of(x) * NBY + bkt_of(y)], 1);
        oxy[pos] = make_float4(x, y, z, sq3(x, y, z));
        osx[pos] = i;
    }
}

// KIND 0: self-KNN curvature (mode 0: tgt -> curv2=outA; mode 1: src, gather warped -> moved=outB)
// KIND 1: warped->tgt KNN, interp curv2, subtract moved, loss -> outA
template <int K, int CPQ, int KIND, int CAP>
__global__ __launch_bounds__(BLOCK)
void knn_kernel(const float* __restrict__ src, const float* __restrict__ tgt,
                const float* __restrict__ flow,
                const float4* __restrict__ ws_xyzw, const int* __restrict__ ws_sidx,
                const int* __restrict__ ws_bs,
                const float* __restrict__ curv2, const float* __restrict__ moved,
                float* __restrict__ outA, float* __restrict__ outB,
                int N, float invB)
{
    constexpr int QPB = BLOCK / CPQ;   // 32 queries/block; 8 lanes = 1 query
    static_assert(CPQ * 4 <= CAP && CPQ * K <= CAP, "CAP too small");
    __shared__ float pool_d[QPB * CAP];
    __shared__ int   pool_i[QPB * CAP];
    __shared__ int   hcnt[QPB];

    const int tid  = threadIdx.x;
    const int ql   = tid / CPQ;
    const int c    = tid % CPQ;
    const int lane = tid & 63;
    const int bpb  = N / QPB;

    int blk = blockIdx.x;
    int mode = 0;
    if (KIND == 0) { int half = gridDim.x >> 1; mode = (blk >= half); blk -= mode ? half : 0; }
    const int b  = blk / bpb;
    const int q0 = (blk % bpb) * QPB;
    const size_t bbase = (size_t)b * N * 3;

    const int qset = (KIND == 0) ? mode : 2;
    const int rset = (KIND == 0) ? mode : 0;
    const float4* sQ  = ws_xyzw + (size_t)(qset * 2 + b) * N;
    const int*    sQi = ws_sidx + (size_t)(qset * 2 + b) * N;
    const float4* sRf = ws_xyzw + (size_t)(rset * 2 + b) * N;
    const int*    sRi = ws_sidx + (size_t)(rset * 2 + b) * N;
    const int*    csR = ws_bs   + (size_t)(rset * 2 + b) * (NCELL + 1);

    const int qpos = q0 + ql;
    const float4 q4 = sQ[qpos];
    const int oqi = sQi[qpos];
    const float qx = q4.x, qy = q4.y, qz = q4.z, qq = q4.w;
    const float m2x = -2.0f * qx, m2y = -2.0f * qy, m2z = -2.0f * qz;
    const int qbase = ql * CAP;

    if (c == 0) hcnt[ql] = 0;

    // ---- phase A: per-query 2D-local window, per-lane float top-4 ----
    int wq;
    if (KIND == 0) wq = qpos - AWIN / 2;                               // own slot
    else           wq = csR[bkt_of(qx) * NBY + bkt_of(qy)] - AWIN / 2; // own cell
    wq = min(max(wq, 0), N - AWIN);

    float a0 = INFINITY, a1 = INFINITY, a2 = INFINITY, a3 = INFINITY;
#pragma unroll
    for (int i = 0; i < AWIN / CPQ; ++i) {   // 16 independent loads
        float4 p = sRf[wq + i * CPQ + c];
        float d = fmaf(m2x, p.x, fmaf(m2y, p.y, fmaf(m2z, p.z, qq + p.w)));
        if (d < a3) {
            a3 = d; float tt;
            if (a3 < a2) { tt = a2; a2 = a3; a3 = tt; }
            if (a2 < a1) { tt = a1; a1 = a2; a2 = tt; }
            if (a1 < a0) { tt = a0; a0 = a1; a1 = tt; }
        }
    }
    {   // role a1: per-lane sorted top-4
        int o = qbase + c * 4;
        pool_d[o] = a0; pool_d[o + 1] = a1; pool_d[o + 2] = a2; pool_d[o + 3] = a3;
    }
    __builtin_amdgcn_wave_barrier();

    float Tv = 0.0f;
    if (c == 0) {   // T = K-th smallest of pooled 32
        int pp[CPQ];
#pragma unroll
        for (int cc = 0; cc < CPQ; ++cc) pp[cc] = 0;
        float kth = INFINITY;
#pragma unroll
        for (int k = 0; k < K; ++k) {
            float bdm = INFINITY; int bc = 0;
#pragma unroll
            for (int cc = 0; cc < CPQ; ++cc) {
                float dd = (pp[cc] < 4) ? pool_d[qbase + cc * 4 + pp[cc]] : INFINITY;
                if (dd < bdm) { bdm = dd; bc = cc; }
            }
            kth = bdm;
#pragma unroll
            for (int cc = 0; cc < CPQ; ++cc) pp[cc] += (bc == cc);
        }
        Tv = kth;
    }
    const float T = __shfl(Tv, lane - c);   // broadcast from group leader
    __builtin_amdgcn_wave_barrier();

    // ---- phase B: scan ball-covering cells (circular y-trim), buffer d<=T ----
    const float s = sqrtf(T);
    const int bxlo = bkt_of(qx - s), bxhi = bkt_of(qx + s);
    for (int bx = bxlo; bx <= bxhi; ++bx) {
        const float colL = XLO + bx * BKW;
        const float dxm = fmaxf(0.0f, fmaxf(colL - qx, qx - (colL + BKW)));
        const float rem = T - dxm * dxm;
        if (rem < 0.0f) continue;
        const float ry = sqrtf(rem);
        int p0 = max(csR[bx * NBY + bkt_of(qy - ry)], 0);
        int p1 = min(csR[bx * NBY + bkt_of(qy + ry) + 1], N);
        for (int p = p0 + c; p < p1; p += 4 * CPQ) {
            const int i1 = p + CPQ, i2 = p + 2 * CPQ, i3 = p + 3 * CPQ;
            const int e = p1 - 1;
            float4 t0 = sRf[p];
            float4 t1 = sRf[min(i1, e)];
            float4 t2 = sRf[min(i2, e)];
            float4 t3 = sRf[min(i3, e)];
            float d0 = fmaf(m2x, t0.x, fmaf(m2y, t0.y, fmaf(m2z, t0.z, qq + t0.w)));
            float d1 = fmaf(m2x, t1.x, fmaf(m2y, t1.y, fmaf(m2z, t1.z, qq + t1.w)));
            float d2 = fmaf(m2x, t2.x, fmaf(m2y, t2.y, fmaf(m2z, t2.z, qq + t2.w)));
            float d3 = fmaf(m2x, t3.x, fmaf(m2y, t3.y, fmaf(m2z, t3.z, qq + t3.w)));
            if (d0 <= T) {
                int slot = atomicAdd(&hcnt[ql], 1);
                if (slot < CAP) { pool_d[qbase + slot] = d0; pool_i[qbase + slot] = sRi[p]; }
            }
            if (i1 < p1 && d1 <= T) {
                int slot = atomicAdd(&hcnt[ql], 1);
                if (slot < CAP) { pool_d[qbase + slot] = d1; pool_i[qbase + slot] = sRi[i1]; }
            }
            if (i2 < p1 && d2 <= T) {
                int slot = atomicAdd(&hcnt[ql], 1);
                if (slot < CAP) { pool_d[qbase + slot] = d2; pool_i[qbase + slot] = sRi[i2]; }
            }
            if (i3 < p1 && d3 <= T) {
                int slot = atomicAdd(&hcnt[ql], 1);
                if (slot < CAP) { pool_d[qbase + slot] = d3; pool_i[qbase + slot] = sRi[i3]; }
            }
        }
    }
    __builtin_amdgcn_wave_barrier();

    // ---- final select: buffer slice-insert, or exact rescan on overflow ----
    const int cnt = min(hcnt[ql], CAP);
    const bool ovf = hcnt[ql] > CAP;   // correctness never depends on CAP
    float nd[K]; int ni[K];
#pragma unroll
    for (int k = 0; k < K; ++k) { nd[k] = INFINITY; ni[k] = 0x7FFFFFFF; }
    if (!ovf) {
        for (int h = c; h < cnt; h += CPQ) {
            float d = pool_d[qbase + h]; int ii = pool_i[qbase + h];
            if (lex_less(d, ii, nd[K - 1], ni[K - 1])) {
                nd[K - 1] = d; ni[K - 1] = ii;
#pragma unroll
                for (int p2 = K - 1; p2 > 0; --p2) {
                    if (lex_less(nd[p2], ni[p2], nd[p2 - 1], ni[p2 - 1])) {
                        float td = nd[p2]; nd[p2] = nd[p2 - 1]; nd[p2 - 1] = td;
                        int ti = ni[p2];  ni[p2] = ni[p2 - 1]; ni[p2 - 1] = ti;
                    }
                }
            }
        }
    } else {
        // exact per-lane insert-rescan of the same region (ascending sorted
        // order per lane; lex restored in the merge)
        for (int bx = bxlo; bx <= bxhi; ++bx) {
            const float colL = XLO + bx * BKW;
            const float dxm = fmaxf(0.0f, fmaxf(colL - qx, qx - (colL + BKW)));
            const float rem = T - dxm * dxm;
            if (rem < 0.0f) continue;
            const float ry = sqrtf(rem);
            int p0 = max(csR[bx * NBY + bkt_of(qy - ry)], 0);
            int p1 = min(csR[bx * NBY + bkt_of(qy + ry) + 1], N);
            for (int p = p0 + c; p < p1; p += CPQ) {
                float4 pt = sRf[p];
                float d = fmaf(m2x, pt.x, fmaf(m2y, pt.y, fmaf(m2z, pt.z, qq + pt.w)));
                int ii = sRi[p];
                if (lex_less(d, ii, nd[K - 1], ni[K - 1])) {
                    nd[K - 1] = d; ni[K - 1] = ii;
#pragma unroll
                    for (int p2 = K - 1; p2 > 0; --p2) {
                        if (lex_less(nd[p2], ni[p2], nd[p2 - 1], ni[p2 - 1])) {
                            float td = nd[p2]; nd[p2] = nd[p2 - 1]; nd[p2 - 1] = td;
                            int ti = ni[p2];  ni[p2] = ni[p2 - 1]; ni[p2 - 1] = ti;
                        }
                    }
                }
            }
        }
    }
    __builtin_amdgcn_wave_barrier();
#pragma unroll
    for (int k = 0; k < K; ++k) {   // role a2: per-lane sorted K-lists
        pool_d[qbase + c * K + k] = nd[k];
        pool_i[qbase + c * K + k] = ni[k];
    }
    __builtin_amdgcn_wave_barrier();

    float sqv = 0.0f;
    if (c == 0) {
        int pp[CPQ];
#pragma unroll
        for (int cc = 0; cc < CPQ; ++cc) pp[cc] = 0;
        float fd[K]; int fi[K];
#pragma unroll
        for (int k = 0; k < K; ++k) {
            float bdm = INFINITY; int bim = 0x7FFFFFFF; int bc = -1;
#pragma unroll
            for (int cc = 0; cc < CPQ; ++cc) {
                float dd = pool_d[qbase + cc * K + pp[cc]];
                int   ii = pool_i[qbase + cc * K + pp[cc]];
                if (lex_less(dd, ii, bdm, bim)) { bdm = dd; bim = ii; bc = cc; }
            }
            fd[k] = bdm; fi[k] = bim;
#pragma unroll
            for (int cc = 0; cc < CPQ; ++cc) pp[cc] += (bc == cc);
        }

        if (KIND == 0) {
            const float* rb   = ((mode == 0) ? tgt : src) + bbase;
            const float* addf = flow + bbase;
            float cx = qx, cy = qy, cz = qz;
            float gx = 0.f, gy = 0.f, gz = 0.f;
            if (mode == 1) {   // center = warped[oqi]
                cx += addf[(size_t)oqi * 3 + 0];
                cy += addf[(size_t)oqi * 3 + 1];
                cz += addf[(size_t)oqi * 3 + 2];
            }
#pragma unroll
            for (int k = 0; k < K; ++k) {
                int j = (fd[k] > RADIUS2) ? fi[0] : fi[k];
                float px = rb[(size_t)j * 3 + 0];
                float py = rb[(size_t)j * 3 + 1];
                float pz = rb[(size_t)j * 3 + 2];
                if (mode == 1) {
                    px += addf[(size_t)j * 3 + 0];
                    py += addf[(size_t)j * 3 + 1];
                    pz += addf[(size_t)j * 3 + 2];
                }
                gx += px - cx; gy += py - cy; gz += pz - cz;
            }
            float* outp = (mode == 0) ? outA : outB;
            outp[bbase + (size_t)oqi * 3 + 0] = gx / 9.0f;
            outp[bbase + (size_t)oqi * 3 + 1] = gy / 9.0f;
            outp[bbase + (size_t)oqi * 3 + 2] = gz / 9.0f;
        } else {
            float w[K]; float wsum = 0.f;
#pragma unroll
            for (int k = 0; k < K; ++k) { w[k] = 1.0f / (fd[k] + 1e-8f); wsum += w[k]; }
            float ix = 0.f, iy = 0.f, iz = 0.f;
#pragma unroll
            for (int k = 0; k < K; ++k) {
                int j = (fd[k] > RADIUS2) ? fi[0] : fi[k];
                float wn = w[k] / wsum;
                ix += wn * curv2[bbase + (size_t)j * 3 + 0];
                iy += wn * curv2[bbase + (size_t)j * 3 + 1];
                iz += wn * curv2[bbase + (size_t)j * 3 + 2];
            }
            float dx = ix - moved[bbase + (size_t)oqi * 3 + 0];
            float dy = iy - moved[bbase + (size_t)oqi * 3 + 1];
            float dz = iz - moved[bbase + (size_t)oqi * 3 + 2];
            sqv = fmaf(dx, dx, fmaf(dy, dy, dz * dz));
        }
    }

    if (KIND == 1) {   // wave reduce -> one global atomic per wave
        float v = sqv;
#pragma unroll
        for (int sft = 1; sft < 64; sft <<= 1) v += __shfl_xor(v, sft);
        if (lane == 0) atomicAdd(outA, v * invB);
    }
}

extern "C" void kernel_launch(void* const* d_in, const int* in_sizes, int n_in,
                              void* d_out, int out_size, void* d_ws, size_t ws_size,
                              hipStream_t stream) {
    const float* src  = (const float*)d_in[0];
    const float* tgt  = (const float*)d_in[1];
    const float* flow = (const float*)d_in[2];
    float* out = (float*)d_out;

    const int B = 2;
    const int N = in_sizes[0] / (B * 3);        // 8192

    float*  curv2  = (float*)d_ws;                         // B*N*3 f32
    float*  moved  = curv2 + (size_t)B * N * 3;            // B*N*3 f32
    float4* xyzw   = (float4*)(moved + (size_t)B * N * 3); // 6*N float4
    int*    sidx   = (int*)(xyzw + (size_t)6 * N);         // 6*N int
    int*    bstart = sidx + (size_t)6 * N;                 // 6*(NCELL+1) int

    hipMemsetAsync(d_out, 0, sizeof(float), stream);

    sort_kernel<<<6, BLOCK, 0, stream>>>(src, tgt, flow, xyzw, sidx, bstart, N);

    // fused self-KNN curvatures: grid = 2 modes * B * N/32 = 1024 blocks
    knn_kernel<10, 8, 0, 112><<<2 * B * (N / 32), BLOCK, 0, stream>>>(
        src, tgt, flow, xyzw, sidx, bstart, nullptr, nullptr, curv2, moved, N, 0.f);

    // interp + loss: grid = B * N/32 = 512 blocks
    knn_kernel<5, 8, 1, 112><<<B * (N / 32), BLOCK, 0, stream>>>(
        src, tgt, flow, xyzw, sidx, bstart, curv2, moved, out, nullptr, N, 1.0f / B);
}

// Round 12
// 904.719 us; speedup vs baseline: 1.2552x; 1.2552x over previous
//
#include <hip/hip_runtime.h>
#include <math.h>

// CurvatureLoss via 2D-cell-pruned exact KNN. B=2, N=8192, [B,N,3] fp32.
// sort: each set {tgt, src, warped=src+flow} into 64x64 (x,y) cells, cell-major.
// knn: BLOCK=64 = ONE wave = 8 queries x 8 lanes. Single instruction stream per
// wave => cross-lane LDS ordering is program order (proven r11); wave_barrier
// only fences compiler reordering. No block-wide sync, no straggler coupling.
//   phase A: 128 cell-contiguous points around q's own slot/cell; per-lane
//     top-4; leader merges pooled 32 -> T = K-th smallest (valid upper bound).
//   phase B: scan cells covering ball(q, sqrt(T)), per-column y-trim; buffer
//     ALL d<=T points exactly once (4-way ILP loads).
//   overflow (hits > CAP, rare): T1 = K-th smallest of the CAP buffered real
//     candidates (tight, still an upper bound) -> cheap __any-gated insert
//     rescan of the SMALL T1-rectangle. Correctness never depends on CAP.
//   final: exact lex (d, orig_idx) top-K == jax.lax.top_k (unique keys).

constexpr int SBLK  = 256;   // sort kernel block
constexpr int BLOCK = 64;    // knn kernel block = 1 wave
constexpr int NBX = 64, NBY = 64, NCELL = NBX * NBY;
constexpr float XLO = -6.0f, XHI = 6.0f;
constexpr float BKW = (XHI - XLO) / NBX;
constexpr float BKS = NBX / (XHI - XLO);
constexpr int AWIN = 128;    // per-query T-sample window
constexpr float RADIUS2 = 2.5f;

__device__ __forceinline__ float sq3(float x, float y, float z) {
    return fmaf(x, x, fmaf(y, y, z * z));
}
__device__ __forceinline__ bool lex_less(float d1, int i1, float d2, int i2) {
    return (d1 < d2) || (d1 == d2 && i1 < i2);
}
__device__ __forceinline__ int bkt_of(float v) {   // monotone with clamp
    int k = (int)((v - XLO) * BKS);
    return k < 0 ? 0 : (k > NBX - 1 ? NBX - 1 : k);
}

// Cell-sort one (set,b): set 0=tgt, 1=src, 2=warped(src+flow). grid = 6 blocks.
__global__ __launch_bounds__(SBLK)
void sort_kernel(const float* __restrict__ src, const float* __restrict__ tgt,
                 const float* __restrict__ flow,
                 float4* __restrict__ xyzw, int* __restrict__ sidx,
                 int* __restrict__ bstart, int N)
{
    const int set = blockIdx.x >> 1;
    const int b   = blockIdx.x & 1;
    const size_t pbase = (size_t)b * N * 3;
    const float* P = (set == 0) ? tgt : src;
    const bool addF = (set == 2);
    float4* oxy = xyzw + (size_t)blockIdx.x * N;
    int*    osx = sidx + (size_t)blockIdx.x * N;
    int*    obs = bstart + (size_t)blockIdx.x * (NCELL + 1);

    __shared__ int hist[NCELL];
    __shared__ int tsum[SBLK];
    const int t = threadIdx.x;
    constexpr int CPT = NCELL / SBLK;   // 16 cells per thread

    for (int k = t; k < NCELL; k += SBLK) hist[k] = 0;
    __syncthreads();
    for (int i = t; i < N; i += SBLK) {
        size_t o = pbase + (size_t)i * 3;
        float x = P[o], y = P[o + 1];
        if (addF) { x += flow[o]; y += flow[o + 1]; }
        atomicAdd(&hist[bkt_of(x) * NBY + bkt_of(y)], 1);
    }
    __syncthreads();
    {
        int base = t * CPT, s = 0;
        for (int m = 0; m < CPT; ++m) s += hist[base + m];
        tsum[t] = s;
    }
    __syncthreads();
    if (t == 0) {
        int run = 0;
        for (int u = 0; u < SBLK; ++u) { int v = tsum[u]; tsum[u] = run; run += v; }
    }
    __syncthreads();
    {
        int base = t * CPT, run = tsum[t];
        for (int m = 0; m < CPT; ++m) {
            int h = hist[base + m];
            hist[base + m] = run;          // scatter cursor
            obs[base + m] = run;           // cell start
            run += h;
        }
    }
    if (t == 0) obs[NCELL] = N;
    __syncthreads();
    for (int i = t; i < N; i += SBLK) {
        size_t o = pbase + (size_t)i * 3;
        float x = P[o], y = P[o + 1], z = P[o + 2];
        if (addF) { x += flow[o]; y += flow[o + 1]; z += flow[o + 2]; }
        int pos = atomicAdd(&hist[bkt_of(x) * NBY + bkt_of(y)], 1);
        oxy[pos] = make_float4(x, y, z, sq3(x, y, z));
        osx[pos] = i;
    }
}

// KIND 0: self-KNN curvature (mode 0: tgt->curv2=outA; mode 1: src, gather warped ->moved=outB)
// KIND 1: warped->tgt KNN, interp curv2, subtract moved, loss -> outA
template <int K, int CPQ, int KIND, int CAP>
__global__ __launch_bounds__(BLOCK)
void knn_kernel(const float* __restrict__ src, const float* __restrict__ tgt,
                const float* __restrict__ flow,
                const float4* __restrict__ ws_xyzw, const int* __restrict__ ws_sidx,
                const int* __restrict__ ws_bs,
                const float* __restrict__ curv2, const float* __restrict__ moved,
                float* __restrict__ outA, float* __restrict__ outB,
                int N, float invB)
{
    constexpr int QPB = BLOCK / CPQ;   // 8 queries per wave-block
    static_assert(CPQ * 4 <= CAP && CPQ * K <= CAP, "CAP too small");
    __shared__ float pool_d[QPB * CAP];
    __shared__ int   pool_i[QPB * CAP];
    __shared__ int   hcnt[QPB];

    const int tid  = threadIdx.x;
    const int ql   = tid / CPQ;
    const int c    = tid % CPQ;
    const int lane = tid;              // BLOCK==64: tid is the lane
    const int bpb  = N / QPB;

    int blk = blockIdx.x;
    int mode = 0;
    if (KIND == 0) { int half = gridDim.x >> 1; mode = (blk >= half); blk -= mode ? half : 0; }
    const int b  = blk / bpb;
    const int q0 = (blk % bpb) * QPB;
    const size_t bbase = (size_t)b * N * 3;

    const int qset = (KIND == 0) ? mode : 2;
    const int rset = (KIND == 0) ? mode : 0;
    const float4* sQ  = ws_xyzw + (size_t)(qset * 2 + b) * N;
    const int*    sQi = ws_sidx + (size_t)(qset * 2 + b) * N;
    const float4* sRf = ws_xyzw + (size_t)(rset * 2 + b) * N;
    const int*    sRi = ws_sidx + (size_t)(rset * 2 + b) * N;
    const int*    csR = ws_bs   + (size_t)(rset * 2 + b) * (NCELL + 1);

    const int qpos = q0 + ql;
    const float4 q4 = sQ[qpos];
    const int oqi = sQi[qpos];
    const float qx = q4.x, qy = q4.y, qz = q4.z, qq = q4.w;
    const float m2x = -2.0f * qx, m2y = -2.0f * qy, m2z = -2.0f * qz;
    const int qbase = ql * CAP;

    if (c == 0) hcnt[ql] = 0;

    // ---- phase A: per-query 2D-local window, per-lane float top-4 ----
    int wq;
    if (KIND == 0) wq = qpos - AWIN / 2;                               // own slot
    else           wq = csR[bkt_of(qx) * NBY + bkt_of(qy)] - AWIN / 2; // own cell
    wq = min(max(wq, 0), N - AWIN);

    float a0 = INFINITY, a1 = INFINITY, a2 = INFINITY, a3 = INFINITY;
#pragma unroll
    for (int i = 0; i < AWIN / CPQ; ++i) {   // 16 independent loads
        float4 p = sRf[wq + i * CPQ + c];
        float d = fmaf(m2x, p.x, fmaf(m2y, p.y, fmaf(m2z, p.z, qq + p.w)));
        if (d < a3) {
            a3 = d; float tt;
            if (a3 < a2) { tt = a2; a2 = a3; a3 = tt; }
            if (a2 < a1) { tt = a1; a1 = a2; a2 = tt; }
            if (a1 < a0) { tt = a0; a0 = a1; a1 = tt; }
        }
    }
    {   // role a1: per-lane sorted top-4
        int o = qbase + c * 4;
        pool_d[o] = a0; pool_d[o + 1] = a1; pool_d[o + 2] = a2; pool_d[o + 3] = a3;
    }
    __builtin_amdgcn_wave_barrier();

    float Tv = 0.0f;
    if (c == 0) {   // T = K-th smallest of pooled 32
        int pp[CPQ];
#pragma unroll
        for (int cc = 0; cc < CPQ; ++cc) pp[cc] = 0;
        float kth = INFINITY;
#pragma unroll
        for (int k = 0; k < K; ++k) {
            float bdm = INFINITY; int bc = 0;
#pragma unroll
            for (int cc = 0; cc < CPQ; ++cc) {
                float dd = (pp[cc] < 4) ? pool_d[qbase + cc * 4 + pp[cc]] : INFINITY;
                if (dd < bdm) { bdm = dd; bc = cc; }
            }
            kth = bdm;
#pragma unroll
            for (int cc = 0; cc < CPQ; ++cc) pp[cc] += (bc == cc);
        }
        Tv = kth;
    }
    const float T = __shfl(Tv, lane - c);
    __builtin_amdgcn_wave_barrier();

    // ---- phase B: scan ball-covering cells (y-trim), buffer ALL d<=T ----
    const float s = sqrtf(T);
    const int bxlo = bkt_of(qx - s), bxhi = bkt_of(qx + s);
    for (int bx = bxlo; bx <= bxhi; ++bx) {
        const float colL = XLO + bx * BKW;
        const float dxm = fmaxf(0.0f, fmaxf(colL - qx, qx - (colL + BKW)));
        const float rem = T - dxm * dxm;
        if (rem < 0.0f) continue;
        const float ry = sqrtf(rem);
        int p0 = max(csR[bx * NBY + bkt_of(qy - ry)], 0);
        int p1 = min(csR[bx * NBY + bkt_of(qy + ry) + 1], N);
        for (int p = p0 + c; p < p1; p += 4 * CPQ) {
            const int i1 = p + CPQ, i2 = p + 2 * CPQ, i3 = p + 3 * CPQ;
            const int e = p1 - 1;
            float4 t0 = sRf[p];
            float4 t1 = sRf[min(i1, e)];
            float4 t2 = sRf[min(i2, e)];
            float4 t3 = sRf[min(i3, e)];
            float d0 = fmaf(m2x, t0.x, fmaf(m2y, t0.y, fmaf(m2z, t0.z, qq + t0.w)));
            float d1 = fmaf(m2x, t1.x, fmaf(m2y, t1.y, fmaf(m2z, t1.z, qq + t1.w)));
            float d2 = fmaf(m2x, t2.x, fmaf(m2y, t2.y, fmaf(m2z, t2.z, qq + t2.w)));
            float d3 = fmaf(m2x, t3.x, fmaf(m2y, t3.y, fmaf(m2z, t3.z, qq + t3.w)));
            if (d0 <= T) {
                int slot = atomicAdd(&hcnt[ql], 1);
                if (slot < CAP) { pool_d[qbase + slot] = d0; pool_i[qbase + slot] = sRi[p]; }
            }
            if (i1 < p1 && d1 <= T) {
                int slot = atomicAdd(&hcnt[ql], 1);
                if (slot < CAP) { pool_d[qbase + slot] = d1; pool_i[qbase + slot] = sRi[i1]; }
            }
            if (i2 < p1 && d2 <= T) {
                int slot = atomicAdd(&hcnt[ql], 1);
                if (slot < CAP) { pool_d[qbase + slot] = d2; pool_i[qbase + slot] = sRi[i2]; }
            }
            if (i3 < p1 && d3 <= T) {
                int slot = atomicAdd(&hcnt[ql], 1);
                if (slot < CAP) { pool_d[qbase + slot] = d3; pool_i[qbase + slot] = sRi[i3]; }
            }
        }
    }
    __builtin_amdgcn_wave_barrier();

    // ---- final select ----
    const int cnt = min(hcnt[ql], CAP);
    const bool ovf = hcnt[ql] > CAP;
    float nd[K]; int ni[K];
#pragma unroll
    for (int k = 0; k < K; ++k) { nd[k] = INFINITY; ni[k] = 0x7FFFFFFF; }

    if (!ovf) {
        // per-lane strided insert over the hit buffer
        for (int h = c; h < cnt; h += CPQ) {
            float d = pool_d[qbase + h]; int ii = pool_i[qbase + h];
            if (lex_less(d, ii, nd[K - 1], ni[K - 1])) {
                nd[K - 1] = d; ni[K - 1] = ii;
#pragma unroll
                for (int p2 = K - 1; p2 > 0; --p2) {
                    if (lex_less(nd[p2], ni[p2], nd[p2 - 1], ni[p2 - 1])) {
                        float td = nd[p2]; nd[p2] = nd[p2 - 1]; nd[p2 - 1] = td;
                        int ti = ni[p2];  ni[p2] = ni[p2 - 1]; ni[p2 - 1] = ti;
                    }
                }
            }
        }
    } else {
        // (1) tighten: T1 = K-th smallest of the CAP buffered real candidates
        float td[K];
#pragma unroll
        for (int k = 0; k < K; ++k) td[k] = INFINITY;
        for (int h = c; h < CAP; h += CPQ) {
            float d = pool_d[qbase + h];
            if (d < td[K - 1]) {
                td[K - 1] = d;
#pragma unroll
                for (int p2 = K - 1; p2 > 0; --p2) {
                    if (td[p2] < td[p2 - 1]) { float tt = td[p2]; td[p2] = td[p2 - 1]; td[p2 - 1] = tt; }
                }
            }
        }
        __builtin_amdgcn_wave_barrier();
#pragma unroll
        for (int k = 0; k < K; ++k) pool_d[qbase + c * K + k] = td[k];
        __builtin_amdgcn_wave_barrier();
        float T1v = 0.0f;
        if (c == 0) {
            int pp[CPQ];
#pragma unroll
            for (int cc = 0; cc < CPQ; ++cc) pp[cc] = 0;
            float kth = INFINITY;
#pragma unroll
            for (int k = 0; k < K; ++k) {
                float bdm = INFINITY; int bc = 0;
#pragma unroll
                for (int cc = 0; cc < CPQ; ++cc) {
                    float dd = pool_d[qbase + cc * K + pp[cc]];
                    if (dd < bdm) { bdm = dd; bc = cc; }
                }
                kth = bdm;
#pragma unroll
                for (int cc = 0; cc < CPQ; ++cc) pp[cc] += (bc == cc);
            }
            T1v = kth;
        }
        const float T1 = __shfl(T1v, lane - c);
        __builtin_amdgcn_wave_barrier();

        // (2) exact insert-rescan of the SMALL T1-rectangle (__any-gated)
        const float s1 = sqrtf(T1);
        const int cxlo = bkt_of(qx - s1), cxhi = bkt_of(qx + s1);
        for (int bx = cxlo; bx <= cxhi; ++bx) {
            const float colL = XLO + bx * BKW;
            const float dxm = fmaxf(0.0f, fmaxf(colL - qx, qx - (colL + BKW)));
            const float rem = T1 - dxm * dxm;
            if (rem < 0.0f) continue;
            const float ry = sqrtf(rem);
            int p0 = max(csR[bx * NBY + bkt_of(qy - ry)], 0);
            int p1 = min(csR[bx * NBY + bkt_of(qy + ry) + 1], N);
            for (int p = p0 + c; p < p1; p += CPQ) {
                float4 pt = sRf[p];
                float d = fmaf(m2x, pt.x, fmaf(m2y, pt.y, fmaf(m2z, pt.z, qq + pt.w)));
                int ii = sRi[p];
                bool pass = lex_less(d, ii, nd[K - 1], ni[K - 1]);
                if (__any(pass)) {
                    if (pass) {
                        nd[K - 1] = d; ni[K - 1] = ii;
#pragma unroll
                        for (int p2 = K - 1; p2 > 0; --p2) {
                            if (lex_less(nd[p2], ni[p2], nd[p2 - 1], ni[p2 - 1])) {
                                float t2 = nd[p2]; nd[p2] = nd[p2 - 1]; nd[p2 - 1] = t2;
                                int ti = ni[p2];  ni[p2] = ni[p2 - 1]; ni[p2 - 1] = ti;
                            }
                        }
                    }
                }
            }
        }
    }
    __builtin_amdgcn_wave_barrier();
#pragma unroll
    for (int k = 0; k < K; ++k) {   // role a2: per-lane sorted K-lists
        pool_d[qbase + c * K + k] = nd[k];
        pool_i[qbase + c * K + k] = ni[k];
    }
    __builtin_amdgcn_wave_barrier();

    float sqv = 0.0f;
    if (c == 0) {
        int pp[CPQ];
#pragma unroll
        for (int cc = 0; cc < CPQ; ++cc) pp[cc] = 0;
        float fd[K]; int fi[K];
#pragma unroll
        for (int k = 0; k < K; ++k) {
            float bdm = INFINITY; int bim = 0x7FFFFFFF; int bc = -1;
#pragma unroll
            for (int cc = 0; cc < CPQ; ++cc) {
                float dd = pool_d[qbase + cc * K + pp[cc]];
                int   ii = pool_i[qbase + cc * K + pp[cc]];
                if (lex_less(dd, ii, bdm, bim)) { bdm = dd; bim = ii; bc = cc; }
            }
            fd[k] = bdm; fi[k] = bim;
#pragma unroll
            for (int cc = 0; cc < CPQ; ++cc) pp[cc] += (bc == cc);
        }

        if (KIND == 0) {
            const float* rb   = ((mode == 0) ? tgt : src) + bbase;
            const float* addf = flow + bbase;
            float cx = qx, cy = qy, cz = qz;
            float gx = 0.f, gy = 0.f, gz = 0.f;
            if (mode == 1) {   // center = warped[oqi]
                cx += addf[(size_t)oqi * 3 + 0];
                cy += addf[(size_t)oqi * 3 + 1];
                cz += addf[(size_t)oqi * 3 + 2];
            }
#pragma unroll
            for (int k = 0; k < K; ++k) {
                int j = (fd[k] > RADIUS2) ? fi[0] : fi[k];
                float px = rb[(size_t)j * 3 + 0];
                float py = rb[(size_t)j * 3 + 1];
                float pz = rb[(size_t)j * 3 + 2];
                if (mode == 1) {
                    px += addf[(size_t)j * 3 + 0];
                    py += addf[(size_t)j * 3 + 1];
                    pz += addf[(size_t)j * 3 + 2];
                }
                gx += px - cx; gy += py - cy; gz += pz - cz;
            }
            float* outp = (mode == 0) ? outA : outB;
            outp[bbase + (size_t)oqi * 3 + 0] = gx / 9.0f;
            outp[bbase + (size_t)oqi * 3 + 1] = gy / 9.0f;
            outp[bbase + (size_t)oqi * 3 + 2] = gz / 9.0f;
        } else {
            float w[K]; float wsum = 0.f;
#pragma unroll
            for (int k = 0; k < K; ++k) { w[k] = 1.0f / (fd[k] + 1e-8f); wsum += w[k]; }
            float ix = 0.f, iy = 0.f, iz = 0.f;
#pragma unroll
            for (int k = 0; k < K; ++k) {
                int j = (fd[k] > RADIUS2) ? fi[0] : fi[k];
                float wn = w[k] / wsum;
                ix += wn * curv2[bbase + (size_t)j * 3 + 0];
                iy += wn * curv2[bbase + (size_t)j * 3 + 1];
                iz += wn * curv2[bbase + (size_t)j * 3 + 2];
            }
            float dx = ix - moved[bbase + (size_t)oqi * 3 + 0];
            float dy = iy - moved[bbase + (size_t)oqi * 3 + 1];
            float dz = iz - moved[bbase + (size_t)oqi * 3 + 2];
            sqv = fmaf(dx, dx, fmaf(dy, dy, dz * dz));
        }
    }

    if (KIND == 1) {   // wave reduce -> one global atomic per wave
        float v = sqv;
#pragma unroll
        for (int sft = 1; sft < 64; sft <<= 1) v += __shfl_xor(v, sft);
        if (lane == 0) atomicAdd(outA, v * invB);
    }
}

extern "C" void kernel_launch(void* const* d_in, const int* in_sizes, int n_in,
                              void* d_out, int out_size, void* d_ws, size_t ws_size,
                              hipStream_t stream) {
    const float* src  = (const float*)d_in[0];
    const float* tgt  = (const float*)d_in[1];
    const float* flow = (const float*)d_in[2];
    float* out = (float*)d_out;

    const int B = 2;
    const int N = in_sizes[0] / (B * 3);        // 8192

    float*  curv2  = (float*)d_ws;                         // B*N*3 f32
    float*  moved  = curv2 + (size_t)B * N * 3;            // B*N*3 f32
    float4* xyzw   = (float4*)(moved + (size_t)B * N * 3); // 6*N float4
    int*    sidx   = (int*)(xyzw + (size_t)6 * N);         // 6*N int
    int*    bstart = sidx + (size_t)6 * N;                 // 6*(NCELL+1) int

    hipMemsetAsync(d_out, 0, sizeof(float), stream);

    sort_kernel<<<6, SBLK, 0, stream>>>(src, tgt, flow, xyzw, sidx, bstart, N);

    // fused self-KNN curvatures: grid = 2 modes * B * N/8 = 4096 one-wave blocks
    knn_kernel<10, 8, 0, 96><<<2 * B * (N / 8), BLOCK, 0, stream>>>(
        src, tgt, flow, xyzw, sidx, bstart, nullptr, nullptr, curv2, moved, N, 0.f);

    // interp + loss: grid = B * N/8 = 2048 one-wave blocks
    knn_kernel<5, 8, 1, 64><<<B * (N / 8), BLOCK, 0, stream>>>(
        src, tgt, flow, xyzw, sidx, bstart, curv2, moved, out, nullptr, N, 1.0f / B);
}

// Round 13
// 649.285 us; speedup vs baseline: 1.7490x; 1.3934x over previous
//
#include <hip/hip_runtime.h>
#include <math.h>

// CurvatureLoss via 2D-cell-pruned exact KNN. B=2, N=8192, [B,N,3] fp32.
// sort: each set {tgt, src, warped=src+flow} into 64x64 (x,y) cells, cell-major.
// knn: BLOCK=256 (4 waves), CPQ=16 lanes per query, 16 queries/block. Each
// query's 16 lanes live in ONE wave (16|64) -> cross-lane LDS traffic is
// ordered by the wave's single instruction stream (proven r11/r12);
// wave_barrier only pins compiler order. No block-wide sync.
//   phase A: 128 cell-contiguous points around q's own slot/cell; per-lane
//     top-4 of 8; leader merges pooled 64 -> T = K-th smallest (upper bound).
//   phase B: scan cells covering ball(q, sqrt(T)), per-column y-trim
//     ry=sqrt(T-dx^2); buffer ALL d<=T points exactly once (4-way ILP loads).
//   overflow (hits > CAP, rare): T1 = K-th smallest of CAP buffered real
//     candidates (tight upper bound) -> exact insert-rescan of the small
//     T1-rectangle. Correctness never depends on CAP (r12-proven).
//   final: exact lex (d, orig_idx) top-K == jax.lax.top_k (unique keys =>
//     deterministic despite atomic scatter order).

constexpr int SBLK  = 256;   // sort kernel block
constexpr int BLOCK = 256;   // knn kernel block (4 waves)
constexpr int NBX = 64, NBY = 64, NCELL = NBX * NBY;
constexpr float XLO = -6.0f, XHI = 6.0f;
constexpr float BKW = (XHI - XLO) / NBX;
constexpr float BKS = NBX / (XHI - XLO);
constexpr int AWIN = 128;    // per-query T-sample window
constexpr float RADIUS2 = 2.5f;

__device__ __forceinline__ float sq3(float x, float y, float z) {
    return fmaf(x, x, fmaf(y, y, z * z));
}
__device__ __forceinline__ bool lex_less(float d1, int i1, float d2, int i2) {
    return (d1 < d2) || (d1 == d2 && i1 < i2);
}
__device__ __forceinline__ int bkt_of(float v) {   // monotone with clamp
    int k = (int)((v - XLO) * BKS);
    return k < 0 ? 0 : (k > NBX - 1 ? NBX - 1 : k);
}

// Cell-sort one (set,b): set 0=tgt, 1=src, 2=warped(src+flow). grid = 6 blocks.
__global__ __launch_bounds__(SBLK)
void sort_kernel(const float* __restrict__ src, const float* __restrict__ tgt,
                 const float* __restrict__ flow,
                 float4* __restrict__ xyzw, int* __restrict__ sidx,
                 int* __restrict__ bstart, int N)
{
    const int set = blockIdx.x >> 1;
    const int b   = blockIdx.x & 1;
    const size_t pbase = (size_t)b * N * 3;
    const float* P = (set == 0) ? tgt : src;
    const bool addF = (set == 2);
    float4* oxy = xyzw + (size_t)blockIdx.x * N;
    int*    osx = sidx + (size_t)blockIdx.x * N;
    int*    obs = bstart + (size_t)blockIdx.x * (NCELL + 1);

    __shared__ int hist[NCELL];
    __shared__ int tsum[SBLK];
    const int t = threadIdx.x;
    constexpr int CPT = NCELL / SBLK;   // 16 cells per thread

    for (int k = t; k < NCELL; k += SBLK) hist[k] = 0;
    __syncthreads();
    for (int i = t; i < N; i += SBLK) {
        size_t o = pbase + (size_t)i * 3;
        float x = P[o], y = P[o + 1];
        if (addF) { x += flow[o]; y += flow[o + 1]; }
        atomicAdd(&hist[bkt_of(x) * NBY + bkt_of(y)], 1);
    }
    __syncthreads();
    {
        int base = t * CPT, s = 0;
        for (int m = 0; m < CPT; ++m) s += hist[base + m];
        tsum[t] = s;
    }
    __syncthreads();
    if (t == 0) {
        int run = 0;
        for (int u = 0; u < SBLK; ++u) { int v = tsum[u]; tsum[u] = run; run += v; }
    }
    __syncthreads();
    {
        int base = t * CPT, run = tsum[t];
        for (int m = 0; m < CPT; ++m) {
            int h = hist[base + m];
            hist[base + m] = run;          // scatter cursor
            obs[base + m] = run;           // cell start
            run += h;
        }
    }
    if (t == 0) obs[NCELL] = N;
    __syncthreads();
    for (int i = t; i < N; i += SBLK) {
        size_t o = pbase + (size_t)i * 3;
        float x = P[o], y = P[o + 1], z = P[o + 2];
        if (addF) { x += flow[o]; y += flow[o + 1]; z += flow[o + 2]; }
        int pos = atomicAdd(&hist[bkt_of(x) * NBY + bkt_of(y)], 1);
        oxy[pos] = make_float4(x, y, z, sq3(x, y, z));
        osx[pos] = i;
    }
}

// KIND 0: self-KNN curvature (mode 0: tgt->curv2=outA; mode 1: src, gather warped ->moved=outB)
// KIND 1: warped->tgt KNN, interp curv2, subtract moved, loss -> outA
template <int K, int CPQ, int KIND, int CAP>
__global__ __launch_bounds__(BLOCK)
void knn_kernel(const float* __restrict__ src, const float* __restrict__ tgt,
                const float* __restrict__ flow,
                const float4* __restrict__ ws_xyzw, const int* __restrict__ ws_sidx,
                const int* __restrict__ ws_bs,
                const float* __restrict__ curv2, const float* __restrict__ moved,
                float* __restrict__ outA, float* __restrict__ outB,
                int N, float invB)
{
    constexpr int QPB = BLOCK / CPQ;   // 16 queries per block
    static_assert(CPQ * 4 <= CAP && CPQ * K <= CAP, "CAP too small");
    static_assert(64 % CPQ == 0, "query group must sit inside one wave");
    __shared__ float pool_d[QPB * CAP];
    __shared__ int   pool_i[QPB * CAP];
    __shared__ int   hcnt[QPB];

    const int tid  = threadIdx.x;
    const int ql   = tid / CPQ;
    const int c    = tid % CPQ;
    const int lane = tid & 63;
    const int bpb  = N / QPB;

    int blk = blockIdx.x;
    int mode = 0;
    if (KIND == 0) { int half = gridDim.x >> 1; mode = (blk >= half); blk -= mode ? half : 0; }
    const int b  = blk / bpb;
    const int q0 = (blk % bpb) * QPB;
    const size_t bbase = (size_t)b * N * 3;

    const int qset = (KIND == 0) ? mode : 2;
    const int rset = (KIND == 0) ? mode : 0;
    const float4* sQ  = ws_xyzw + (size_t)(qset * 2 + b) * N;
    const int*    sQi = ws_sidx + (size_t)(qset * 2 + b) * N;
    const float4* sRf = ws_xyzw + (size_t)(rset * 2 + b) * N;
    const int*    sRi = ws_sidx + (size_t)(rset * 2 + b) * N;
    const int*    csR = ws_bs   + (size_t)(rset * 2 + b) * (NCELL + 1);

    const int qpos = q0 + ql;
    const float4 q4 = sQ[qpos];
    const int oqi = sQi[qpos];
    const float qx = q4.x, qy = q4.y, qz = q4.z, qq = q4.w;
    const float m2x = -2.0f * qx, m2y = -2.0f * qy, m2z = -2.0f * qz;
    const int qbase = ql * CAP;

    if (c == 0) hcnt[ql] = 0;

    // ---- phase A: per-query 2D-local window, per-lane float top-4 of 8 ----
    int wq;
    if (KIND == 0) wq = qpos - AWIN / 2;                               // own slot
    else           wq = csR[bkt_of(qx) * NBY + bkt_of(qy)] - AWIN / 2; // own cell
    wq = min(max(wq, 0), N - AWIN);

    float a0 = INFINITY, a1 = INFINITY, a2 = INFINITY, a3 = INFINITY;
#pragma unroll
    for (int i = 0; i < AWIN / CPQ; ++i) {   // independent loads -> 1 epoch
        float4 p = sRf[wq + i * CPQ + c];
        float d = fmaf(m2x, p.x, fmaf(m2y, p.y, fmaf(m2z, p.z, qq + p.w)));
        if (d < a3) {
            a3 = d; float tt;
            if (a3 < a2) { tt = a2; a2 = a3; a3 = tt; }
            if (a2 < a1) { tt = a1; a1 = a2; a2 = tt; }
            if (a1 < a0) { tt = a0; a0 = a1; a1 = tt; }
        }
    }
    {   // role a1: per-lane sorted top-4
        int o = qbase + c * 4;
        pool_d[o] = a0; pool_d[o + 1] = a1; pool_d[o + 2] = a2; pool_d[o + 3] = a3;
    }
    __builtin_amdgcn_wave_barrier();

    float Tv = 0.0f;
    if (c == 0) {   // T = K-th smallest of pooled CPQ*4 samples
        int pp[CPQ];
#pragma unroll
        for (int cc = 0; cc < CPQ; ++cc) pp[cc] = 0;
        float kth = INFINITY;
#pragma unroll
        for (int k = 0; k < K; ++k) {
            float bdm = INFINITY; int bc = 0;
#pragma unroll
            for (int cc = 0; cc < CPQ; ++cc) {
                float dd = (pp[cc] < 4) ? pool_d[qbase + cc * 4 + pp[cc]] : INFINITY;
                if (dd < bdm) { bdm = dd; bc = cc; }
            }
            kth = bdm;
#pragma unroll
            for (int cc = 0; cc < CPQ; ++cc) pp[cc] += (bc == cc);
        }
        Tv = kth;
    }
    const float T = __shfl(Tv, lane - c);   // broadcast from group leader
    __builtin_amdgcn_wave_barrier();

    // ---- phase B: scan ball-covering cells (y-trim), buffer ALL d<=T ----
    const float s = sqrtf(T);
    const int bxlo = bkt_of(qx - s), bxhi = bkt_of(qx + s);
    for (int bx = bxlo; bx <= bxhi; ++bx) {
        const float colL = XLO + bx * BKW;
        const float dxm = fmaxf(0.0f, fmaxf(colL - qx, qx - (colL + BKW)));
        const float rem = T - dxm * dxm;
        if (rem < 0.0f) continue;
        const float ry = sqrtf(rem);
        int p0 = max(csR[bx * NBY + bkt_of(qy - ry)], 0);
        int p1 = min(csR[bx * NBY + bkt_of(qy + ry) + 1], N);
        for (int p = p0 + c; p < p1; p += 4 * CPQ) {
            const int i1 = p + CPQ, i2 = p + 2 * CPQ, i3 = p + 3 * CPQ;
            const int e = p1 - 1;
            float4 t0 = sRf[p];
            float4 t1 = sRf[min(i1, e)];
            float4 t2 = sRf[min(i2, e)];
            float4 t3 = sRf[min(i3, e)];
            float d0 = fmaf(m2x, t0.x, fmaf(m2y, t0.y, fmaf(m2z, t0.z, qq + t0.w)));
            float d1 = fmaf(m2x, t1.x, fmaf(m2y, t1.y, fmaf(m2z, t1.z, qq + t1.w)));
            float d2 = fmaf(m2x, t2.x, fmaf(m2y, t2.y, fmaf(m2z, t2.z, qq + t2.w)));
            float d3 = fmaf(m2x, t3.x, fmaf(m2y, t3.y, fmaf(m2z, t3.z, qq + t3.w)));
            if (d0 <= T) {
                int slot = atomicAdd(&hcnt[ql], 1);
                if (slot < CAP) { pool_d[qbase + slot] = d0; pool_i[qbase + slot] = sRi[p]; }
            }
            if (i1 < p1 && d1 <= T) {
                int slot = atomicAdd(&hcnt[ql], 1);
                if (slot < CAP) { pool_d[qbase + slot] = d1; pool_i[qbase + slot] = sRi[i1]; }
            }
            if (i2 < p1 && d2 <= T) {
                int slot = atomicAdd(&hcnt[ql], 1);
                if (slot < CAP) { pool_d[qbase + slot] = d2; pool_i[qbase + slot] = sRi[i2]; }
            }
            if (i3 < p1 && d3 <= T) {
                int slot = atomicAdd(&hcnt[ql], 1);
                if (slot < CAP) { pool_d[qbase + slot] = d3; pool_i[qbase + slot] = sRi[i3]; }
            }
        }
    }
    __builtin_amdgcn_wave_barrier();

    // ---- final select ----
    const int cnt = min(hcnt[ql], CAP);
    const bool ovf = hcnt[ql] > CAP;
    float nd[K]; int ni[K];
#pragma unroll
    for (int k = 0; k < K; ++k) { nd[k] = INFINITY; ni[k] = 0x7FFFFFFF; }

    if (!ovf) {
        for (int h = c; h < cnt; h += CPQ) {
            float d = pool_d[qbase + h]; int ii = pool_i[qbase + h];
            if (lex_less(d, ii, nd[K - 1], ni[K - 1])) {
                nd[K - 1] = d; ni[K - 1] = ii;
#pragma unroll
                for (int p2 = K - 1; p2 > 0; --p2) {
                    if (lex_less(nd[p2], ni[p2], nd[p2 - 1], ni[p2 - 1])) {
                        float td = nd[p2]; nd[p2] = nd[p2 - 1]; nd[p2 - 1] = td;
                        int ti = ni[p2];  ni[p2] = ni[p2 - 1]; ni[p2 - 1] = ti;
                    }
                }
            }
        }
    } else {
        // (1) tighten: T1 = K-th smallest of the CAP buffered real candidates
        float td[K];
#pragma unroll
        for (int k = 0; k < K; ++k) td[k] = INFINITY;
        for (int h = c; h < CAP; h += CPQ) {
            float d = pool_d[qbase + h];
            if (d < td[K - 1]) {
                td[K - 1] = d;
#pragma unroll
                for (int p2 = K - 1; p2 > 0; --p2) {
                    if (td[p2] < td[p2 - 1]) { float tt = td[p2]; td[p2] = td[p2 - 1]; td[p2 - 1] = tt; }
                }
            }
        }
        __builtin_amdgcn_wave_barrier();
#pragma unroll
        for (int k = 0; k < K; ++k) pool_d[qbase + c * K + k] = td[k];
        __builtin_amdgcn_wave_barrier();
        float T1v = 0.0f;
        if (c == 0) {
            int pp[CPQ];
#pragma unroll
            for (int cc = 0; cc < CPQ; ++cc) pp[cc] = 0;
            float kth = INFINITY;
#pragma unroll
            for (int k = 0; k < K; ++k) {
                float bdm = INFINITY; int bc = 0;
#pragma unroll
                for (int cc = 0; cc < CPQ; ++cc) {
                    float dd = pool_d[qbase + cc * K + pp[cc]];
                    if (dd < bdm) { bdm = dd; bc = cc; }
                }
                kth = bdm;
#pragma unroll
                for (int cc = 0; cc < CPQ; ++cc) pp[cc] += (bc == cc);
            }
            T1v = kth;
        }
        const float T1 = __shfl(T1v, lane - c);
        __builtin_amdgcn_wave_barrier();

        // (2) exact insert-rescan of the SMALL T1-rectangle (__any-gated)
        const float s1 = sqrtf(T1);
        const int cxlo = bkt_of(qx - s1), cxhi = bkt_of(qx + s1);
        for (int bx = cxlo; bx <= cxhi; ++bx) {
            const float colL = XLO + bx * BKW;
            const float dxm = fmaxf(0.0f, fmaxf(colL - qx, qx - (colL + BKW)));
            const float rem = T1 - dxm * dxm;
            if (rem < 0.0f) continue;
            const float ry = sqrtf(rem);
            int p0 = max(csR[bx * NBY + bkt_of(qy - ry)], 0);
            int p1 = min(csR[bx * NBY + bkt_of(qy + ry) + 1], N);
            for (int p = p0 + c; p < p1; p += CPQ) {
                float4 pt = sRf[p];
                float d = fmaf(m2x, pt.x, fmaf(m2y, pt.y, fmaf(m2z, pt.z, qq + pt.w)));
                int ii = sRi[p];
                bool pass = lex_less(d, ii, nd[K - 1], ni[K - 1]);
                if (__any(pass)) {
                    if (pass) {
                        nd[K - 1] = d; ni[K - 1] = ii;
#pragma unroll
                        for (int p2 = K - 1; p2 > 0; --p2) {
                            if (lex_less(nd[p2], ni[p2], nd[p2 - 1], ni[p2 - 1])) {
                                float t2 = nd[p2]; nd[p2] = nd[p2 - 1]; nd[p2 - 1] = t2;
                                int ti = ni[p2];  ni[p2] = ni[p2 - 1]; ni[p2 - 1] = ti;
                            }
                        }
                    }
                }
            }
        }
    }
    __builtin_amdgcn_wave_barrier();
#pragma unroll
    for (int k = 0; k < K; ++k) {   // role a2: per-lane sorted K-lists
        pool_d[qbase + c * K + k] = nd[k];
        pool_i[qbase + c * K + k] = ni[k];
    }
    __builtin_amdgcn_wave_barrier();

    float sqv = 0.0f;
    if (c == 0) {
        int pp[CPQ];
#pragma unroll
        for (int cc = 0; cc < CPQ; ++cc) pp[cc] = 0;
        float fd[K]; int fi[K];
#pragma unroll
        for (int k = 0; k < K; ++k) {
            float bdm = INFINITY; int bim = 0x7FFFFFFF; int bc = -1;
#pragma unroll
            for (int cc = 0; cc < CPQ; ++cc) {
                float dd = pool_d[qbase + cc * K + pp[cc]];
                int   ii = pool_i[qbase + cc * K + pp[cc]];
                if (lex_less(dd, ii, bdm, bim)) { bdm = dd; bim = ii; bc = cc; }
            }
            fd[k] = bdm; fi[k] = bim;
#pragma unroll
            for (int cc = 0; cc < CPQ; ++cc) pp[cc] += (bc == cc);
        }

        if (KIND == 0) {
            const float* rb   = ((mode == 0) ? tgt : src) + bbase;
            const float* addf = flow + bbase;
            float cx = qx, cy = qy, cz = qz;
            float gx = 0.f, gy = 0.f, gz = 0.f;
            if (mode == 1) {   // center = warped[oqi]
                cx += addf[(size_t)oqi * 3 + 0];
                cy += addf[(size_t)oqi * 3 + 1];
                cz += addf[(size_t)oqi * 3 + 2];
            }
#pragma unroll
            for (int k = 0; k < K; ++k) {
                int j = (fd[k] > RADIUS2) ? fi[0] : fi[k];
                float px = rb[(size_t)j * 3 + 0];
                float py = rb[(size_t)j * 3 + 1];
                float pz = rb[(size_t)j * 3 + 2];
                if (mode == 1) {
                    px += addf[(size_t)j * 3 + 0];
                    py += addf[(size_t)j * 3 + 1];
                    pz += addf[(size_t)j * 3 + 2];
                }
                gx += px - cx; gy += py - cy; gz += pz - cz;
            }
            float* outp = (mode == 0) ? outA : outB;
            outp[bbase + (size_t)oqi * 3 + 0] = gx / 9.0f;
            outp[bbase + (size_t)oqi * 3 + 1] = gy / 9.0f;
            outp[bbase + (size_t)oqi * 3 + 2] = gz / 9.0f;
        } else {
            float w[K]; float wsum = 0.f;
#pragma unroll
            for (int k = 0; k < K; ++k) { w[k] = 1.0f / (fd[k] + 1e-8f); wsum += w[k]; }
            float ix = 0.f, iy = 0.f, iz = 0.f;
#pragma unroll
            for (int k = 0; k < K; ++k) {
                int j = (fd[k] > RADIUS2) ? fi[0] : fi[k];
                float wn = w[k] / wsum;
                ix += wn * curv2[bbase + (size_t)j * 3 + 0];
                iy += wn * curv2[bbase + (size_t)j * 3 + 1];
                iz += wn * curv2[bbase + (size_t)j * 3 + 2];
            }
            float dx = ix - moved[bbase + (size_t)oqi * 3 + 0];
            float dy = iy - moved[bbase + (size_t)oqi * 3 + 1];
            float dz = iz - moved[bbase + (size_t)oqi * 3 + 2];
            sqv = fmaf(dx, dx, fmaf(dy, dy, dz * dz));
        }
    }

    if (KIND == 1) {   // wave reduce -> one global atomic per wave
        float v = sqv;
#pragma unroll
        for (int sft = 1; sft < 64; sft <<= 1) v += __shfl_xor(v, sft);
        if (lane == 0) atomicAdd(outA, v * invB);
    }
}

extern "C" void kernel_launch(void* const* d_in, const int* in_sizes, int n_in,
                              void* d_out, int out_size, void* d_ws, size_t ws_size,
                              hipStream_t stream) {
    const float* src  = (const float*)d_in[0];
    const float* tgt  = (const float*)d_in[1];
    const float* flow = (const float*)d_in[2];
    float* out = (float*)d_out;

    const int B = 2;
    const int N = in_sizes[0] / (B * 3);        // 8192

    float*  curv2  = (float*)d_ws;                         // B*N*3 f32
    float*  moved  = curv2 + (size_t)B * N * 3;            // B*N*3 f32
    float4* xyzw   = (float4*)(moved + (size_t)B * N * 3); // 6*N float4
    int*    sidx   = (int*)(xyzw + (size_t)6 * N);         // 6*N int
    int*    bstart = sidx + (size_t)6 * N;                 // 6*(NCELL+1) int

    hipMemsetAsync(d_out, 0, sizeof(float), stream);

    sort_kernel<<<6, SBLK, 0, stream>>>(src, tgt, flow, xyzw, sidx, bstart, N);

    // fused self-KNN curvatures: CPQ=16, QPB=16 -> 2*B*N/16 = 2048 blocks
    knn_kernel<10, 16, 0, 160><<<2 * B * (N / 16), BLOCK, 0, stream>>>(
        src, tgt, flow, xyzw, sidx, bstart, nullptr, nullptr, curv2, moved, N, 0.f);

    // interp + loss: B*N/16 = 1024 blocks
    knn_kernel<5, 16, 1, 128><<<B * (N / 16), BLOCK, 0, stream>>>(
        src, tgt, flow, xyzw, sidx, bstart, curv2, moved, out, nullptr, N, 1.0f / B);
}

// Round 14
// 309.132 us; speedup vs baseline: 3.6736x; 2.1004x over previous
//
#include <hip/hip_runtime.h>
#include <math.h>

// CurvatureLoss via x-sorted window KNN with block-uniform loops.
// B=2, N=8192, [B,N,3] fp32. sort: each set {tgt, src, warped} by x into 256
// buckets (monotone clamped). knn per block: 16 queries x 16 lanes; the 1024
// sorted points around the block's queries are staged ONCE in LDS.
//   phase A: per-lane float top-4 over the LDS window (uniform 64 iters);
//     leader merges pooled 64 -> T = K-th smallest (valid upper bound on the
//     true K-th distance: order statistic of a >=K-subset of real candidates).
//   phase B: re-filter the SAME LDS window with d<=T (d<=T implies the point
//     is in q's x-range, no range test needed) + block-union x-slivers outside
//     the window (global reads, identical addrs across query groups). Buffer
//     ALL d<=T points exactly once -> >=K guaranteed.
//   overflow (hits>CAP, rare): per-lane lex insert-RESCAN of window+slivers
//     (no cross-lane handoff -> legal in divergent branch). Correctness never
//     depends on CAP.
//   final: exact lex (d, orig_idx) top-K == jax.lax.top_k (unique keys =>
//     deterministic despite atomic scatter order). Epilogues byte-identical
//     to the absmax-0.0 rounds.

constexpr int SBLK  = 256;
constexpr int BLOCK = 256;
constexpr int NB1   = 256;           // 1D x-buckets
constexpr float XLO = -8.0f, XHI = 8.0f;
constexpr float BKS = NB1 / (XHI - XLO);
constexpr int WPTS  = 1024;          // LDS window
constexpr float RADIUS2 = 2.5f;

__device__ __forceinline__ float sq3(float x, float y, float z) {
    return fmaf(x, x, fmaf(y, y, z * z));
}
__device__ __forceinline__ bool lex_less(float d1, int i1, float d2, int i2) {
    return (d1 < d2) || (d1 == d2 && i1 < i2);
}
__device__ __forceinline__ int bkt1(float v) {   // monotone with clamp
    int k = (int)((v - XLO) * BKS);
    return k < 0 ? 0 : (k > NB1 - 1 ? NB1 - 1 : k);
}

// x-bucket sort one (set,b): set 0=tgt, 1=src, 2=warped. grid = 6 blocks.
__global__ __launch_bounds__(SBLK)
void sort_kernel(const float* __restrict__ src, const float* __restrict__ tgt,
                 const float* __restrict__ flow,
                 float4* __restrict__ xyzw, int* __restrict__ sidx,
                 int* __restrict__ bstart, int N)
{
    const int set = blockIdx.x >> 1;
    const int b   = blockIdx.x & 1;
    const size_t pbase = (size_t)b * N * 3;
    const float* P = (set == 0) ? tgt : src;
    const bool addF = (set == 2);
    float4* oxy = xyzw + (size_t)blockIdx.x * N;
    int*    osx = sidx + (size_t)blockIdx.x * N;
    int*    obs = bstart + (size_t)blockIdx.x * (NB1 + 1);

    __shared__ int hist[NB1];
    __shared__ int scan[NB1 + 1];
    const int t = threadIdx.x;   // SBLK == NB1: thread t owns bucket t

    hist[t] = 0;
    __syncthreads();
    for (int i = t; i < N; i += SBLK) {
        float x = P[pbase + (size_t)i * 3];
        if (addF) x += flow[pbase + (size_t)i * 3];
        atomicAdd(&hist[bkt1(x)], 1);
    }
    __syncthreads();
    if (t == 0) {
        int run = 0;
        for (int k = 0; k < NB1; ++k) { scan[k] = run; run += hist[k]; }
        scan[NB1] = run;
    }
    __syncthreads();
    obs[t] = scan[t];
    if (t == 0) obs[NB1] = scan[NB1];
    hist[t] = scan[t];               // scatter cursor
    __syncthreads();
    for (int i = t; i < N; i += SBLK) {
        size_t o = pbase + (size_t)i * 3;
        float x = P[o], y = P[o + 1], z = P[o + 2];
        if (addF) { x += flow[o]; y += flow[o + 1]; z += flow[o + 2]; }
        int pos = atomicAdd(&hist[bkt1(x)], 1);
        oxy[pos] = make_float4(x, y, z, sq3(x, y, z));
        osx[pos] = i;
    }
}

// KIND 0: self-KNN curvature (mode 0: tgt->curv2=outA; mode 1: src, gather warped->moved=outB)
// KIND 1: warped->tgt KNN, interp curv2, subtract moved, loss -> outA
template <int K, int CPQ, int KIND, int CAP>
__global__ __launch_bounds__(BLOCK)
void knn_kernel(const float* __restrict__ src, const float* __restrict__ tgt,
                const float* __restrict__ flow,
                const float4* __restrict__ ws_xyzw, const int* __restrict__ ws_sidx,
                const int* __restrict__ ws_bs,
                const float* __restrict__ curv2, const float* __restrict__ moved,
                float* __restrict__ outA, float* __restrict__ outB,
                int N, float invB)
{
    constexpr int QPB = BLOCK / CPQ;   // 16 queries/block; 16 lanes in ONE wave
    static_assert(CPQ * 4 <= CAP && CPQ * K <= CAP, "CAP too small");
    static_assert(64 % CPQ == 0, "query group must sit inside one wave");
    __shared__ float4 swin[WPTS];
    __shared__ float  pool_d[QPB * CAP];
    __shared__ int    pool_i[QPB * CAP];
    __shared__ int    sbs[NB1 + 1];
    __shared__ float  Tsh[QPB];
    __shared__ int    hcnt[QPB];
    __shared__ int    uminS, umaxS;
    __shared__ float  lsum;

    const int tid = threadIdx.x;
    const int ql  = tid / CPQ;
    const int c   = tid % CPQ;
    const int bpb = N / QPB;

    int blk = blockIdx.x;
    int mode = 0;
    if (KIND == 0) { int half = gridDim.x >> 1; mode = (blk >= half); blk -= mode ? half : 0; }
    const int b  = blk / bpb;
    const int q0 = (blk % bpb) * QPB;
    const size_t bbase = (size_t)b * N * 3;

    const int qset = (KIND == 0) ? mode : 2;
    const int rset = (KIND == 0) ? mode : 0;
    const float4* sQ  = ws_xyzw + (size_t)(qset * 2 + b) * N;
    const int*    sQi = ws_sidx + (size_t)(qset * 2 + b) * N;
    const float4* sRf = ws_xyzw + (size_t)(rset * 2 + b) * N;
    const int*    sRi = ws_sidx + (size_t)(rset * 2 + b) * N;
    const int*    bsR = ws_bs   + (size_t)(rset * 2 + b) * (NB1 + 1);

    const int qpos = q0 + ql;
    const float4 q4 = sQ[qpos];
    const int oqi = sQi[qpos];
    const float qx = q4.x, qy = q4.y, qz = q4.z, qq = q4.w;
    const float m2x = -2.0f * qx, m2y = -2.0f * qy, m2z = -2.0f * qz;
    const int qbase = ql * CAP;

    // ---- stage bucket table + window (block-uniform) ----
    for (int k = tid; k <= NB1; k += BLOCK) sbs[k] = bsR[k];

    int wA0;
    if (KIND == 0) {
        wA0 = q0 + QPB / 2 - WPTS / 2;
    } else {
        float xm = sQ[q0 + QPB / 2].x;
        wA0 = bsR[bkt1(xm)] - WPTS / 2;
    }
    wA0 = min(max(wA0, 0), N - WPTS);
    const int wA1 = wA0 + WPTS;

    for (int j = tid; j < WPTS; j += BLOCK) swin[j] = sRf[wA0 + j];
    if (tid == 0) { uminS = wA0; umaxS = wA1; lsum = 0.0f; }
    if (c == 0) hcnt[ql] = 0;
    __syncthreads();

    // ---- phase A: per-lane float top-4 over the window (uniform) ----
    float a0 = INFINITY, a1 = INFINITY, a2 = INFINITY, a3 = INFINITY;
#pragma unroll 8
    for (int i = 0; i < WPTS / CPQ; ++i) {
        float4 p = swin[i * CPQ + c];   // same addr for all query groups: broadcast
        float d = fmaf(m2x, p.x, fmaf(m2y, p.y, fmaf(m2z, p.z, qq + p.w)));
        if (d < a3) {
            a3 = d; float tt;
            if (a3 < a2) { tt = a2; a2 = a3; a3 = tt; }
            if (a2 < a1) { tt = a1; a1 = a2; a2 = tt; }
            if (a1 < a0) { tt = a0; a0 = a1; a1 = tt; }
        }
    }
    {   // role a1: per-lane sorted top-4
        int o = qbase + c * 4;
        pool_d[o] = a0; pool_d[o + 1] = a1; pool_d[o + 2] = a2; pool_d[o + 3] = a3;
    }
    __syncthreads();

    if (c == 0) {   // T = K-th smallest of pooled CPQ*4 (upper bound, near-tight)
        int pp[CPQ];
#pragma unroll
        for (int cc = 0; cc < CPQ; ++cc) pp[cc] = 0;
        float kth = INFINITY;
#pragma unroll
        for (int k = 0; k < K; ++k) {
            float bdm = INFINITY; int bc = 0;
#pragma unroll
            for (int cc = 0; cc < CPQ; ++cc) {
                float dd = (pp[cc] < 4) ? pool_d[qbase + cc * 4 + pp[cc]] : INFINITY;
                if (dd < bdm) { bdm = dd; bc = cc; }
            }
            kth = bdm;
#pragma unroll
            for (int cc = 0; cc < CPQ; ++cc) pp[cc] += (bc == cc);
        }
        Tsh[ql] = kth;
        float s = sqrtf(kth);
        atomicMin(&uminS, sbs[bkt1(qx - s)]);
        atomicMax(&umaxS, sbs[bkt1(qx + s) + 1]);
    }
    __syncthreads();
    const float T = Tsh[ql];
    const int um = max(uminS, 0), uM = min(umaxS, N);

    // ---- phase B1: filter the LDS window (d<=T implies in-range) ----
    for (int i = 0; i < WPTS / CPQ; ++i) {
        const int j = i * CPQ + c;
        float4 p = swin[j];
        float d = fmaf(m2x, p.x, fmaf(m2y, p.y, fmaf(m2z, p.z, qq + p.w)));
        bool hit = d <= T;
        if (__any(hit)) {
            if (hit) {
                int slot = atomicAdd(&hcnt[ql], 1);
                if (slot < CAP) { pool_d[qbase + slot] = d; pool_i[qbase + slot] = sRi[wA0 + j]; }
            }
        }
    }
    // ---- phase B2: block-union slivers outside the window (global) ----
    for (int seg = 0; seg < 2; ++seg) {
        const int s0 = seg ? wA1 : um;
        const int s1 = seg ? uM  : wA0;
        for (int p = s0 + c; p < s1; p += CPQ) {
            float4 pt = sRf[p];
            float d = fmaf(m2x, pt.x, fmaf(m2y, pt.y, fmaf(m2z, pt.z, qq + pt.w)));
            bool hit = d <= T;
            if (__any(hit)) {
                if (hit) {
                    int slot = atomicAdd(&hcnt[ql], 1);
                    if (slot < CAP) { pool_d[qbase + slot] = d; pool_i[qbase + slot] = sRi[p]; }
                }
            }
        }
    }
    __syncthreads();

    // ---- final select: buffer insert, or exact rescan on overflow ----
    const int cnt = min(hcnt[ql], CAP);
    const bool ovf = hcnt[ql] > CAP;
    float nd[K]; int ni[K];
#pragma unroll
    for (int k = 0; k < K; ++k) { nd[k] = INFINITY; ni[k] = 0x7FFFFFFF; }

    if (!ovf) {
        for (int h = c; h < cnt; h += CPQ) {
            float d = pool_d[qbase + h]; int ii = pool_i[qbase + h];
            if (lex_less(d, ii, nd[K - 1], ni[K - 1])) {
                nd[K - 1] = d; ni[K - 1] = ii;
#pragma unroll
                for (int p2 = K - 1; p2 > 0; --p2) {
                    if (lex_less(nd[p2], ni[p2], nd[p2 - 1], ni[p2 - 1])) {
                        float td = nd[p2]; nd[p2] = nd[p2 - 1]; nd[p2 - 1] = td;
                        int ti = ni[p2];  ni[p2] = ni[p2 - 1]; ni[p2 - 1] = ti;
                    }
                }
            }
        }
    } else {
        // exact rescan: window (LDS, read-only) + slivers (global); per-lane
        // lex insert, no cross-lane handoff -> safe in divergent branch
        for (int i = 0; i < WPTS / CPQ; ++i) {
            const int j = i * CPQ + c;
            float4 p = swin[j];
            float d = fmaf(m2x, p.x, fmaf(m2y, p.y, fmaf(m2z, p.z, qq + p.w)));
            int ii = sRi[wA0 + j];
            bool pass = lex_less(d, ii, nd[K - 1], ni[K - 1]);
            if (__any(pass)) {
                if (pass) {
                    nd[K - 1] = d; ni[K - 1] = ii;
#pragma unroll
                    for (int p2 = K - 1; p2 > 0; --p2) {
                        if (lex_less(nd[p2], ni[p2], nd[p2 - 1], ni[p2 - 1])) {
                            float t2 = nd[p2]; nd[p2] = nd[p2 - 1]; nd[p2 - 1] = t2;
                            int ti = ni[p2];  ni[p2] = ni[p2 - 1]; ni[p2 - 1] = ti;
                        }
                    }
                }
            }
        }
        for (int seg = 0; seg < 2; ++seg) {
            const int s0 = seg ? wA1 : um;
            const int s1 = seg ? uM  : wA0;
            for (int p = s0 + c; p < s1; p += CPQ) {
                float4 pt = sRf[p];
                float d = fmaf(m2x, pt.x, fmaf(m2y, pt.y, fmaf(m2z, pt.z, qq + pt.w)));
                int ii = sRi[p];
                bool pass = lex_less(d, ii, nd[K - 1], ni[K - 1]);
                if (__any(pass)) {
                    if (pass) {
                        nd[K - 1] = d; ni[K - 1] = ii;
#pragma unroll
                        for (int p2 = K - 1; p2 > 0; --p2) {
                            if (lex_less(nd[p2], ni[p2], nd[p2 - 1], ni[p2 - 1])) {
                                float t2 = nd[p2]; nd[p2] = nd[p2 - 1]; nd[p2 - 1] = t2;
                                int ti = ni[p2];  ni[p2] = ni[p2 - 1]; ni[p2 - 1] = ti;
                            }
                        }
                    }
                }
            }
        }
    }
    __syncthreads();   // hit buffer consumed
#pragma unroll
    for (int k = 0; k < K; ++k) {   // role a2: per-lane sorted K-lists
        pool_d[qbase + c * K + k] = nd[k];
        pool_i[qbase + c * K + k] = ni[k];
    }
    __syncthreads();

    if (c == 0) {
        int pp[CPQ];
#pragma unroll
        for (int cc = 0; cc < CPQ; ++cc) pp[cc] = 0;
        float fd[K]; int fi[K];
#pragma unroll
        for (int k = 0; k < K; ++k) {
            float bdm = INFINITY; int bim = 0x7FFFFFFF; int bc = -1;
#pragma unroll
            for (int cc = 0; cc < CPQ; ++cc) {
                float dd = pool_d[qbase + cc * K + pp[cc]];
                int   ii = pool_i[qbase + cc * K + pp[cc]];
                if (lex_less(dd, ii, bdm, bim)) { bdm = dd; bim = ii; bc = cc; }
            }
            fd[k] = bdm; fi[k] = bim;
#pragma unroll
            for (int cc = 0; cc < CPQ; ++cc) pp[cc] += (bc == cc);
        }

        if (KIND == 0) {
            const float* rb   = ((mode == 0) ? tgt : src) + bbase;
            const float* addf = flow + bbase;
            float cx = qx, cy = qy, cz = qz;
            float gx = 0.f, gy = 0.f, gz = 0.f;
            if (mode == 1) {   // center = warped[oqi]
                cx += addf[(size_t)oqi * 3 + 0];
                cy += addf[(size_t)oqi * 3 + 1];
                cz += addf[(size_t)oqi * 3 + 2];
            }
#pragma unroll
            for (int k = 0; k < K; ++k) {
                int j = (fd[k] > RADIUS2) ? fi[0] : fi[k];
                float px = rb[(size_t)j * 3 + 0];
                float py = rb[(size_t)j * 3 + 1];
                float pz = rb[(size_t)j * 3 + 2];
                if (mode == 1) {
                    px += addf[(size_t)j * 3 + 0];
                    py += addf[(size_t)j * 3 + 1];
                    pz += addf[(size_t)j * 3 + 2];
                }
                gx += px - cx; gy += py - cy; gz += pz - cz;
            }
            float* outp = (mode == 0) ? outA : outB;
            outp[bbase + (size_t)oqi * 3 + 0] = gx / 9.0f;
            outp[bbase + (size_t)oqi * 3 + 1] = gy / 9.0f;
            outp[bbase + (size_t)oqi * 3 + 2] = gz / 9.0f;
        } else {
            float w[K]; float wsum = 0.f;
#pragma unroll
            for (int k = 0; k < K; ++k) { w[k] = 1.0f / (fd[k] + 1e-8f); wsum += w[k]; }
            float ix = 0.f, iy = 0.f, iz = 0.f;
#pragma unroll
            for (int k = 0; k < K; ++k) {
                int j = (fd[k] > RADIUS2) ? fi[0] : fi[k];
                float wn = w[k] / wsum;
                ix += wn * curv2[bbase + (size_t)j * 3 + 0];
                iy += wn * curv2[bbase + (size_t)j * 3 + 1];
                iz += wn * curv2[bbase + (size_t)j * 3 + 2];
            }
            float dx = ix - moved[bbase + (size_t)oqi * 3 + 0];
            float dy = iy - moved[bbase + (size_t)oqi * 3 + 1];
            float dz = iz - moved[bbase + (size_t)oqi * 3 + 2];
            float sqv = fmaf(dx, dx, fmaf(dy, dy, dz * dz));
            atomicAdd(&lsum, sqv);
        }
    }

    if (KIND == 1) {
        __syncthreads();
        if (tid == 0) atomicAdd(outA, lsum * invB);
    }
}

extern "C" void kernel_launch(void* const* d_in, const int* in_sizes, int n_in,
                              void* d_out, int out_size, void* d_ws, size_t ws_size,
                              hipStream_t stream) {
    const float* src  = (const float*)d_in[0];
    const float* tgt  = (const float*)d_in[1];
    const float* flow = (const float*)d_in[2];
    float* out = (float*)d_out;

    const int B = 2;
    const int N = in_sizes[0] / (B * 3);        // 8192

    float*  curv2  = (float*)d_ws;                         // B*N*3 f32
    float*  moved  = curv2 + (size_t)B * N * 3;            // B*N*3 f32
    float4* xyzw   = (float4*)(moved + (size_t)B * N * 3); // 6*N float4
    int*    sidx   = (int*)(xyzw + (size_t)6 * N);         // 6*N int
    int*    bstart = sidx + (size_t)6 * N;                 // 6*(NB1+1) int

    hipMemsetAsync(d_out, 0, sizeof(float), stream);

    sort_kernel<<<6, SBLK, 0, stream>>>(src, tgt, flow, xyzw, sidx, bstart, N);

    // fused self-KNN curvatures: CPQ=16, QPB=16 -> 2*B*N/16 = 2048 blocks
    knn_kernel<10, 16, 0, 160><<<2 * B * (N / 16), BLOCK, 0, stream>>>(
        src, tgt, flow, xyzw, sidx, bstart, nullptr, nullptr, curv2, moved, N, 0.f);

    // interp + loss: B*N/16 = 1024 blocks
    knn_kernel<5, 16, 1, 96><<<B * (N / 16), BLOCK, 0, stream>>>(
        src, tgt, flow, xyzw, sidx, bstart, curv2, moved, out, nullptr, N, 1.0f / B);
}